// Round 12
// baseline (60.311 us; speedup 1.0000x reference)
//
#include <hip/hip_runtime.h>
#include <hip/hip_bf16.h>
#include <math.h>

#define B_ 4
#define L_ 2048
#define H_ 8
#define E_ 64
#define HE 512   // H_*E_ : float stride between consecutive seq positions

typedef short bf16x8 __attribute__((ext_vector_type(8)));
typedef float f32x4 __attribute__((ext_vector_type(4)));
typedef float f32x2 __attribute__((ext_vector_type(2)));
typedef unsigned short u16x4 __attribute__((ext_vector_type(4)));
typedef unsigned short u16x8 __attribute__((ext_vector_type(8)));

__device__ __forceinline__ unsigned short f2b(float f) {
  return __builtin_bit_cast(unsigned short, (__hip_bfloat16)f);
}

// Flash attention fwd, causal, tau-scaled.
// R12 = R4's verified 8-wave/16q-per-wave inner loop (fastest per-unit:
// ~1.85us vs 3.3us for all 32q-per-wave variants) + R11's verified uniform
// two-phase pairing (every block runs exactly 17 serial tile-units):
//   phase A: q-tile j,    kv tiles [0, j+1)
//   phase B: q-tile 15-j, kv tiles [16-j, 32-2j)
// Partials (unnormalized O + m,l) -> d_out/d_ws; combine kernel merges.
// Inner loop: 16x16x32 MFMA, swapped QK^T (S^T=K Q^T), kv-permuted P->PV
// (no LDS P), defer-max (T13), T14 early loads, dbuf swizzled LDS, setprio.
__global__ __launch_bounds__(512, 1) void attn_fwd(
    const float* __restrict__ Q, const float* __restrict__ K,
    const float* __restrict__ V, const float* __restrict__ tau,
    float* __restrict__ O, float* __restrict__ wsOB,
    float* __restrict__ mA, float* __restrict__ lA,
    float* __restrict__ mB, float* __restrict__ lB)
{
  const int f  = blockIdx.x + 16 * (blockIdx.y + 8 * blockIdx.z);  // 0..511
  const int j  = f >> 5, hb = f & 31;          // (b,h) per f&31 -> XCD-local
  const int h  = hb & 7, b = hb >> 3;

  const int tid  = threadIdx.x;
  const int wave = tid >> 6, lane = tid & 63;
  const int lg = lane >> 4, ll = lane & 15;
  const int llm = ll & 7;

  __shared__ unsigned short ldsK[2][64 * 64];  // [buf][kv][e], swizzled
  __shared__ unsigned short ldsV[2][64 * 64];  // [buf][d][kv], swizzled

  const float qscale = 0.125f * expf(tau[b]) * 1.44269504088896f;

  // staging maps (R4): K: row=tid>>3, cols (tid&7)*8..+7 (2 f32x4)
  //                    V: rows 4*(tid>>5)+i, cols (tid&31)*2..+1 (4 f32x2)
  const int krow = tid >> 3, kc8 = tid & 7;
  const int vrow = tid >> 5, vc = (tid & 31) * 2;
  const size_t bh = ((size_t)b * L_ * H_ + h) * E_;
  const int kw_off = krow * 64 + ((kc8 ^ (krow & 7)) << 3);

  auto run_phase = [&](int jj, int t0, int t1,
                       float* Opart, float* mout, float* lout) {
    const int q0w = jj * 128 + wave * 16;      // wave's first q-row
    const int tmaxw = 2 * jj + (wave >> 2);    // wave's diagonal tile

    // Q fragments (B operand): qf[ek][jd] = Q[q0w+ll][32ek + 8lg + jd]
    const float* Qb = Q + (((size_t)b * L_ + (q0w + ll)) * H_ + h) * E_;
    bf16x8 qf[2];
    #pragma unroll
    for (int ek = 0; ek < 2; ++ek) {
      f32x4 a = *(const f32x4*)(Qb + ek * 32 + lg * 8);
      f32x4 c = *(const f32x4*)(Qb + ek * 32 + lg * 8 + 4);
      #pragma unroll
      for (int jd = 0; jd < 4; ++jd) {
        qf[ek][jd]     = (short)f2b(a[jd] * qscale);
        qf[ek][4 + jd] = (short)f2b(c[jd] * qscale);
      }
    }

    float m_run = -INFINITY, l_run = 0.0f;     // stats of q = q0w+ll
    f32x4 oacc[4];
    #pragma unroll
    for (int n = 0; n < 4; ++n) {
      oacc[n][0] = 0.f; oacc[n][1] = 0.f; oacc[n][2] = 0.f; oacc[n][3] = 0.f;
    }

    f32x4 k0, k1; f32x2 v0, v1, v2, v3;
    auto load_tile = [&](int t) {
      const float* Kn = K + bh + (size_t)(64 * t + krow) * HE + kc8 * 8;
      const float* Vn = V + bh + (size_t)(64 * t + 4 * vrow) * HE + vc;
      k0 = *(const f32x4*)(Kn);
      k1 = *(const f32x4*)(Kn + 4);
      v0 = *(const f32x2*)(Vn);
      v1 = *(const f32x2*)(Vn + HE);
      v2 = *(const f32x2*)(Vn + 2 * HE);
      v3 = *(const f32x2*)(Vn + 3 * HE);
    };
    auto stage_write = [&](int nb) {
      u16x8 kw;
      #pragma unroll
      for (int jd = 0; jd < 4; ++jd) { kw[jd] = f2b(k0[jd]); kw[4 + jd] = f2b(k1[jd]); }
      *(u16x8*)(&ldsK[nb][kw_off]) = kw;
      #pragma unroll
      for (int jj2 = 0; jj2 < 2; ++jj2) {
        const int row = vc + jj2;
        u16x4 vw;
        vw[0] = f2b(v0[jj2]); vw[1] = f2b(v1[jj2]);
        vw[2] = f2b(v2[jj2]); vw[3] = f2b(v3[jj2]);
        *(u16x4*)(&ldsV[nb][row * 64 + (((vrow >> 1) ^ (row & 7)) << 3) + 4 * (vrow & 1)]) = vw;
      }
    };

    __syncthreads();               // prior phase's LDS reads done
    load_tile(t0);
    stage_write(0);
    __syncthreads();
    int cur = 0;

    for (int t = t0; t < t1; ++t) {
      const bool havenext = (t + 1 < t1);
      if (havenext) load_tile(t + 1);          // T14: issue loads early

      if (t <= tmaxw) {
        const unsigned short* Kl = ldsK[cur];
        const unsigned short* Vl = ldsV[cur];

        // ---- S^T = K Q^T : 8 MFMAs ----
        f32x4 sacc[4];
        #pragma unroll
        for (int n = 0; n < 4; ++n) {
          sacc[n][0] = 0.f; sacc[n][1] = 0.f; sacc[n][2] = 0.f; sacc[n][3] = 0.f;
        }
        __builtin_amdgcn_s_setprio(1);
        #pragma unroll
        for (int ek = 0; ek < 2; ++ek) {
          #pragma unroll
          for (int n = 0; n < 4; ++n) {
            bf16x8 kf = *(const bf16x8*)(Kl + (16 * n + ll) * 64 +
                                         ((((ek << 2) + lg) ^ llm) << 3));
            sacc[n] = __builtin_amdgcn_mfma_f32_16x16x32_bf16(kf, qf[ek], sacc[n], 0, 0, 0);
          }
        }
        __builtin_amdgcn_s_setprio(0);

        // ---- causal mask (diagonal tile only) ----
        if (t == tmaxw) {
          const int dq = q0w + ll - 64 * t;    // keep kv_local <= dq
          #pragma unroll
          for (int m = 0; m < 4; ++m)
            #pragma unroll
            for (int r = 0; r < 4; ++r)
              if (16 * m + 4 * lg + r > dq) sacc[m][r] = -3.0e38f;
        }

        // ---- online softmax: balanced max tree + defer-max (T13) ----
        float t0m = fmaxf(fmaxf(sacc[0][0], sacc[0][1]), fmaxf(sacc[0][2], sacc[0][3]));
        float t1m = fmaxf(fmaxf(sacc[1][0], sacc[1][1]), fmaxf(sacc[1][2], sacc[1][3]));
        float t2m = fmaxf(fmaxf(sacc[2][0], sacc[2][1]), fmaxf(sacc[2][2], sacc[2][3]));
        float t3m = fmaxf(fmaxf(sacc[3][0], sacc[3][1]), fmaxf(sacc[3][2], sacc[3][3]));
        float mx = fmaxf(fmaxf(t0m, t1m), fmaxf(t2m, t3m));
        mx = fmaxf(mx, __shfl_xor(mx, 16));
        mx = fmaxf(mx, __shfl_xor(mx, 32));

        if (!__all(mx - m_run <= 8.0f)) {      // rescale needed (rare)
          const float mnew = fmaxf(m_run, mx);
          const float corr = exp2f(m_run - mnew);   // first tile: exp2(-inf)=0
          m_run = mnew;
          l_run *= corr;
          #pragma unroll
          for (int r = 0; r < 4; ++r) {
            const float cr = __shfl(corr, 4 * lg + r);
            #pragma unroll
            for (int n = 0; n < 4; ++n) oacc[n][r] *= cr;
          }
        }

        #pragma unroll
        for (int m = 0; m < 4; ++m)
          #pragma unroll
          for (int r = 0; r < 4; ++r)
            sacc[m][r] = exp2f(sacc[m][r] - m_run);

        float s0 = (sacc[0][0] + sacc[0][1]) + (sacc[0][2] + sacc[0][3]);
        float s1 = (sacc[1][0] + sacc[1][1]) + (sacc[1][2] + sacc[1][3]);
        float s2 = (sacc[2][0] + sacc[2][1]) + (sacc[2][2] + sacc[2][3]);
        float s3 = (sacc[3][0] + sacc[3][1]) + (sacc[3][2] + sacc[3][3]);
        float rs = (s0 + s1) + (s2 + s3);
        rs += __shfl_xor(rs, 16);
        rs += __shfl_xor(rs, 32);
        l_run += rs;

        // ---- P frags: lane's own values, packed in permuted-kv order ----
        bf16x8 pf[2];
        #pragma unroll
        for (int ek = 0; ek < 2; ++ek)
          #pragma unroll
          for (int r = 0; r < 4; ++r) {
            pf[ek][r]     = (short)f2b(sacc[2 * ek][r]);
            pf[ek][4 + r] = (short)f2b(sacc[2 * ek + 1][r]);
          }

        // ---- O += P V : 8 MFMAs; V^T frags via union (no repack) ----
        __builtin_amdgcn_s_setprio(1);
        #pragma unroll
        for (int ek = 0; ek < 2; ++ek) {
          #pragma unroll
          for (int n = 0; n < 4; ++n) {
            const int d = 16 * n + ll;
            const int base = d * 64 + 4 * (lg & 1);
            union { bf16x8 v8; u16x4 q[2]; } vu;
            vu.q[0] = *(const u16x4*)(Vl + base +
                         ((((ek << 2) + (lg >> 1)) ^ llm) << 3));
            vu.q[1] = *(const u16x4*)(Vl + base +
                         ((((ek << 2) + 2 + (lg >> 1)) ^ llm) << 3));
            oacc[n] = __builtin_amdgcn_mfma_f32_16x16x32_bf16(pf[ek], vu.v8, oacc[n], 0, 0, 0);
          }
        }
        __builtin_amdgcn_s_setprio(0);
      }

      if (havenext) {
        stage_write(cur ^ 1);
        __syncthreads();
        cur ^= 1;
      }
    }

    // ---- write unnormalized partial + (m,l) ----
    float* Ob = Opart + (((size_t)b * L_ + q0w) * H_ + h) * E_;
    #pragma unroll
    for (int r = 0; r < 4; ++r) {
      const int qrow = lg * 4 + r;
      #pragma unroll
      for (int n = 0; n < 4; ++n)
        Ob[(size_t)qrow * HE + n * 16 + ll] = oacc[n][r];
    }
    if (lg == 0) {
      const int qh = (b * L_ + q0w + ll) * H_ + h;
      mout[qh] = m_run;
      lout[qh] = l_run;
    }
  };

  run_phase(j, 0, j + 1, O, mA, lA);                    // phase A
  run_phase(15 - j, 16 - j, 32 - 2 * j, wsOB, mB, lB);  // phase B
}

// merge the two online-softmax partials and normalize
__global__ __launch_bounds__(256) void attn_combine(
    float* __restrict__ O, const float* __restrict__ wsOB,
    const float* __restrict__ mA, const float* __restrict__ lA,
    const float* __restrict__ mB, const float* __restrict__ lB)
{
  const int idx = blockIdx.x * 256 + threadIdx.x;       // float4 index
  const int qh = idx >> 4;                              // 16 float4 per row
  const float ma = mA[qh], la = lA[qh];
  const float mb = mB[qh], lb = lB[qh];
  const float m = fmaxf(ma, mb);
  const float wa = exp2f(ma - m), wb = exp2f(mb - m);   // exp2(-inf)=0
  const float inv = 1.0f / (wa * la + wb * lb);
  const f32x4 oa = ((const f32x4*)O)[idx];
  const f32x4 ob = ((const f32x4*)wsOB)[idx];
  f32x4 out;
  #pragma unroll
  for (int i = 0; i < 4; ++i) out[i] = (oa[i] * wa + ob[i] * wb) * inv;
  ((f32x4*)O)[idx] = out;
}

extern "C" void kernel_launch(void* const* d_in, const int* in_sizes, int n_in,
                              void* d_out, int out_size, void* d_ws, size_t ws_size,
                              hipStream_t stream) {
  (void)in_sizes; (void)n_in; (void)out_size; (void)ws_size;
  const float* Q   = (const float*)d_in[0];
  const float* K   = (const float*)d_in[1];
  const float* V   = (const float*)d_in[2];
  // d_in[3] = attn_mask: ignored, causality applied analytically.
  const float* tau = (const float*)d_in[4];
  float* O = (float*)d_out;

  float* wsOB = (float*)d_ws;                    // B*L*H*E f32 = 16.8 MB
  float* mA = wsOB + (size_t)B_ * L_ * H_ * E_;  // B*L*H each
  float* lA = mA + (size_t)B_ * L_ * H_;
  float* mB = lA + (size_t)B_ * L_ * H_;
  float* lB = mB + (size_t)B_ * L_ * H_;

  dim3 grid(16, 8, 4), block(512);
  hipLaunchKernelGGL(attn_fwd, grid, block, 0, stream,
                     Q, K, V, tau, O, wsOB, mA, lA, mB, lB);
  const int total4 = B_ * L_ * H_ * E_ / 4;      // 1,048,576
  hipLaunchKernelGGL(attn_combine, dim3(total4 / 256), dim3(256), 0, stream,
                     O, wsOB, mA, lA, mB, lB);
}

// Round 13
// 58.905 us; speedup vs baseline: 1.0239x; 1.0239x over previous
//
#include <hip/hip_runtime.h>
#include <hip/hip_bf16.h>
#include <math.h>

#define B_ 4
#define L_ 2048
#define H_ 8
#define E_ 64
#define HE 512   // H_*E_ : float stride between consecutive seq positions

typedef short bf16x8 __attribute__((ext_vector_type(8)));
typedef float f32x4 __attribute__((ext_vector_type(4)));
typedef float f32x2 __attribute__((ext_vector_type(2)));
typedef unsigned short u16x4 __attribute__((ext_vector_type(4)));
typedef unsigned short u16x8 __attribute__((ext_vector_type(8)));

__device__ __forceinline__ unsigned short f2b(float f) {
  return __builtin_bit_cast(unsigned short, (__hip_bfloat16)f);
}
__device__ __forceinline__ unsigned cvtpk(float lo, float hi) {
  unsigned r;
  asm("v_cvt_pk_bf16_f32 %0, %1, %2" : "=v"(r) : "v"(lo), "v"(hi));
  return r;
}

// Flash attention fwd, causal, tau-scaled.
// R13: OCCUPANCY PUSH. 1024 blocks (64 q-rows each, 32 per (b,h)) x 8 waves,
// KV tile 32, LDS 34KB -> target 3-4 blocks/CU (24-32 waves, vs 16 before).
// Intra-block even/odd kv-split (waves 0-3 / 4-7) + LDS merge (R10-proven).
// Inner loop: 16x16x32 MFMA, swapped QK^T (lane-local softmax), P-pack via
// v_cvt_pk_bf16_f32 (4 instrs), V^T in stride-36 LDS rows (18d mod 32 covers
// all banks -> conflict-free PV reads, no swizzle ALU), defer-max (T13),
// T14 early loads, double-buffered LDS, setprio (T5).
// Per-CU balance: blocks {a, 31-a, a+8, 23-a} (one bh) = 66 half-units.
__global__ __launch_bounds__(512, 6) void attn_fwd(
    const float* __restrict__ Q, const float* __restrict__ K,
    const float* __restrict__ V, const float* __restrict__ tau,
    float* __restrict__ O)
{
  const int hb = blockIdx.x;                   // (b,h): fast dim -> per-CU
  const int h  = hb & 7, b = hb >> 3;
  const int u  = blockIdx.y + 8 * blockIdx.z;  // 0..31
  // balanced bijective remap: CU's 4 blocks {a,31-a,a+8,23-a} -> 66 units
  const int qt = (u < 8) ? u : (u < 16) ? 39 - u : (u < 24) ? u - 8 : 47 - u;

  const int tid  = threadIdx.x;
  const int wave = tid >> 6, lane = tid & 63;
  const int lg = lane >> 4, ll = lane & 15, llm = ll & 7;
  const int half = wave >> 2, wv = wave & 3;   // kv parity, q-subtile

  __shared__ union {
    struct { unsigned short Kt[2][2][32 * 64];   // [half][buf][kv32][e]
             unsigned short Vt[2][2][64 * 36]; } kv;  // [half][buf][d][kv36]
    struct { float O[64][64]; float m[64]; float l[64]; } cmb;
  } sm;

  const float qscale = 0.125f * expf(tau[b]) * 1.44269504088896f;
  const int q0w = qt * 64 + wv * 16;           // wave's first q-row
  const int tmaxw = 2 * qt + (wv >> 1);        // wave's diagonal 32kv-tile

  // Q fragments (B operand): qf[ek][jd] = Q[q0w+ll][32ek + 8lg + jd]
  const float* Qb = Q + (((size_t)b * L_ + (q0w + ll)) * H_ + h) * E_;
  bf16x8 qf[2];
  #pragma unroll
  for (int ek = 0; ek < 2; ++ek) {
    f32x4 a = *(const f32x4*)(Qb + ek * 32 + lg * 8);
    f32x4 c = *(const f32x4*)(Qb + ek * 32 + lg * 8 + 4);
    #pragma unroll
    for (int jd = 0; jd < 4; ++jd) {
      qf[ek][jd]     = (short)f2b(a[jd] * qscale);
      qf[ek][4 + jd] = (short)f2b(c[jd] * qscale);
    }
  }

  float m_run = -INFINITY, l_run = 0.0f;       // stats of q = q0w+ll
  f32x4 oacc[4];
  #pragma unroll
  for (int n = 0; n < 4; ++n) {
    oacc[n][0] = 0.f; oacc[n][1] = 0.f; oacc[n][2] = 0.f; oacc[n][3] = 0.f;
  }

  // ---- staging maps: threads <256 stage half 0 (even tiles), else odd ----
  const int hs = tid >> 8, st = tid & 255;
  const int krow = st >> 3, kc8 = st & 7;      // K: 32 rows x 8 col-groups
  const int vrow = st >> 5, vc = (st & 31) * 2;// V: kv 4vrow..+3, d vc..vc+1
  const size_t bh = ((size_t)b * L_ * H_ + h) * E_;
  const int kw_off = krow * 64 + ((kc8 ^ (krow & 7)) << 3);

  f32x4 k0, k1; f32x2 v0, v1, v2, v3;
  auto load_tile = [&](int t32) {              // 32-kv tile index
    const float* Kn = K + bh + (size_t)(32 * t32 + krow) * HE + kc8 * 8;
    const float* Vn = V + bh + (size_t)(32 * t32 + 4 * vrow) * HE + vc;
    k0 = *(const f32x4*)(Kn);
    k1 = *(const f32x4*)(Kn + 4);
    v0 = *(const f32x2*)(Vn);
    v1 = *(const f32x2*)(Vn + HE);
    v2 = *(const f32x2*)(Vn + 2 * HE);
    v3 = *(const f32x2*)(Vn + 3 * HE);
  };
  auto stage_write = [&](int nb) {
    u16x8 kw;
    #pragma unroll
    for (int jd = 0; jd < 4; ++jd) { kw[jd] = f2b(k0[jd]); kw[4 + jd] = f2b(k1[jd]); }
    *(u16x8*)(&sm.kv.Kt[hs][nb][kw_off]) = kw;
    #pragma unroll
    for (int jj = 0; jj < 2; ++jj) {
      const int row = vc + jj;                 // d-row, stride 36
      u16x4 vw;
      vw[0] = f2b(v0[jj]); vw[1] = f2b(v1[jj]);
      vw[2] = f2b(v2[jj]); vw[3] = f2b(v3[jj]);
      *(u16x4*)(&sm.kv.Vt[hs][nb][row * 36 + 4 * vrow]) = vw;
    }
  };

  const int niter = qt + 1;                    // pair-iterations
  load_tile(hs);
  stage_write(0);
  __syncthreads();
  int cur = 0;

  for (int i = 0; i < niter; ++i) {
    const int t = 2 * i + half;                // this half's 32kv tile
    const bool havenext = (i + 1 < niter);
    if (havenext) load_tile(2 * (i + 1) + hs); // T14: issue loads early

    if (t <= tmaxw) {
      const unsigned short* Kl = sm.kv.Kt[half][cur];
      const unsigned short* Vl = sm.kv.Vt[half][cur];

      // ---- S^T = K Q^T : 4 MFMAs ----
      f32x4 sacc[2];
      #pragma unroll
      for (int m = 0; m < 2; ++m) {
        sacc[m][0] = 0.f; sacc[m][1] = 0.f; sacc[m][2] = 0.f; sacc[m][3] = 0.f;
      }
      __builtin_amdgcn_s_setprio(1);
      #pragma unroll
      for (int ek = 0; ek < 2; ++ek) {
        #pragma unroll
        for (int m = 0; m < 2; ++m) {
          bf16x8 kf = *(const bf16x8*)(Kl + (16 * m + ll) * 64 +
                                       ((((ek << 2) + lg) ^ llm) << 3));
          sacc[m] = __builtin_amdgcn_mfma_f32_16x16x32_bf16(kf, qf[ek], sacc[m], 0, 0, 0);
        }
      }
      __builtin_amdgcn_s_setprio(0);

      // ---- causal mask (diagonal tile only) ----
      if (t == tmaxw) {
        const int dq = q0w + ll - 32 * t;      // keep kv_local <= dq
        #pragma unroll
        for (int m = 0; m < 2; ++m)
          #pragma unroll
          for (int r = 0; r < 4; ++r)
            if (16 * m + 4 * lg + r > dq) sacc[m][r] = -3.0e38f;
      }

      // ---- online softmax (8 values/lane) + defer-max (T13) ----
      float m0 = fmaxf(fmaxf(sacc[0][0], sacc[0][1]), fmaxf(sacc[0][2], sacc[0][3]));
      float m1 = fmaxf(fmaxf(sacc[1][0], sacc[1][1]), fmaxf(sacc[1][2], sacc[1][3]));
      float mx = fmaxf(m0, m1);
      mx = fmaxf(mx, __shfl_xor(mx, 16));
      mx = fmaxf(mx, __shfl_xor(mx, 32));

      if (!__all(mx - m_run <= 8.0f)) {        // rescale needed (rare)
        const float mnew = fmaxf(m_run, mx);
        const float corr = exp2f(m_run - mnew);   // first tile: exp2(-inf)=0
        m_run = mnew;
        l_run *= corr;
        #pragma unroll
        for (int r = 0; r < 4; ++r) {
          const float cr = __shfl(corr, 4 * lg + r);
          #pragma unroll
          for (int n = 0; n < 4; ++n) oacc[n][r] *= cr;
        }
      }

      #pragma unroll
      for (int m = 0; m < 2; ++m)
        #pragma unroll
        for (int r = 0; r < 4; ++r)
          sacc[m][r] = exp2f(sacc[m][r] - m_run);

      float rs = ((sacc[0][0] + sacc[0][1]) + (sacc[0][2] + sacc[0][3]))
               + ((sacc[1][0] + sacc[1][1]) + (sacc[1][2] + sacc[1][3]));
      rs += __shfl_xor(rs, 16);
      rs += __shfl_xor(rs, 32);
      l_run += rs;

      // ---- P frag: 4 x v_cvt_pk_bf16_f32 (pf[r]=sacc[0][r], pf[4+r]=sacc[1][r]) ----
      union { unsigned w[4]; bf16x8 v; } pu;
      pu.w[0] = cvtpk(sacc[0][0], sacc[0][1]);
      pu.w[1] = cvtpk(sacc[0][2], sacc[0][3]);
      pu.w[2] = cvtpk(sacc[1][0], sacc[1][1]);
      pu.w[3] = cvtpk(sacc[1][2], sacc[1][3]);

      // ---- O += P V : 4 MFMAs; V^T stride-36 rows, conflict-free ----
      __builtin_amdgcn_s_setprio(1);
      #pragma unroll
      for (int n = 0; n < 4; ++n) {
        const int d = 16 * n + ll;
        union { bf16x8 v8; u16x4 q[2]; } vu;
        vu.q[0] = *(const u16x4*)(Vl + d * 36 + 4 * lg);       // kv 4lg..+3
        vu.q[1] = *(const u16x4*)(Vl + d * 36 + 16 + 4 * lg);  // kv 16+4lg..+3
        oacc[n] = __builtin_amdgcn_mfma_f32_16x16x32_bf16(pu.v, vu.v8, oacc[n], 0, 0, 0);
      }
      __builtin_amdgcn_s_setprio(0);
    }

    if (havenext) {
      stage_write(cur ^ 1);
      __syncthreads();
      cur ^= 1;
    }
  }

  // ---- merge the two kv-halves (LDS aliases K/V buffers; barriered) ----
  __syncthreads();                  // all compute LDS reads done
  if (half == 1) {                  // publish unnormalized state
    #pragma unroll
    for (int r = 0; r < 4; ++r) {
      const int qrow = 4 * lg + r;
      #pragma unroll
      for (int n = 0; n < 4; ++n)
        sm.cmb.O[16 * wv + qrow][16 * n + ll] = oacc[n][r];
    }
    if (lg == 0) { sm.cmb.m[16 * wv + ll] = m_run; sm.cmb.l[16 * wv + ll] = l_run; }
  }
  __syncthreads();
  if (half == 0) {                  // merge + normalize + store
    const float m_b = sm.cmb.m[16 * wv + ll];
    const float l_b = sm.cmb.l[16 * wv + ll];
    const float mm = fmaxf(m_run, m_b);
    const float sa = exp2f(m_run - mm);
    const float sb = exp2f(m_b - mm);          // m_b=-inf (empty half) -> 0
    const float linv = 1.0f / (sa * l_run + sb * l_b);
    const float wa = sa * linv, wb = sb * linv;
    float* Ob = O + (((size_t)b * L_ + q0w) * H_ + h) * E_;
    #pragma unroll
    for (int r = 0; r < 4; ++r) {
      const int qrow = 4 * lg + r;
      const float wa_r = __shfl(wa, qrow);
      const float wb_r = __shfl(wb, qrow);
      #pragma unroll
      for (int n = 0; n < 4; ++n)
        Ob[(size_t)qrow * HE + 16 * n + ll] =
            wa_r * oacc[n][r] + wb_r * sm.cmb.O[16 * wv + qrow][16 * n + ll];
    }
  }
}

extern "C" void kernel_launch(void* const* d_in, const int* in_sizes, int n_in,
                              void* d_out, int out_size, void* d_ws, size_t ws_size,
                              hipStream_t stream) {
  (void)in_sizes; (void)n_in; (void)out_size; (void)d_ws; (void)ws_size;
  const float* Q   = (const float*)d_in[0];
  const float* K   = (const float*)d_in[1];
  const float* V   = (const float*)d_in[2];
  // d_in[3] = attn_mask: ignored, causality applied analytically.
  const float* tau = (const float*)d_in[4];
  float* O = (float*)d_out;
  dim3 grid(32, 8, 4), block(512);             // x = (b,h); y+8z = q-block
  hipLaunchKernelGGL(attn_fwd, grid, block, 0, stream, Q, K, V, tau, O);
}

// Round 16
// 54.556 us; speedup vs baseline: 1.1055x; 1.0797x over previous
//
#include <hip/hip_runtime.h>
#include <hip/hip_bf16.h>
#include <math.h>

#define B_ 4
#define L_ 2048
#define H_ 8
#define E_ 64
#define HE 512   // H_*E_ : float stride between consecutive seq positions

typedef short bf16x8 __attribute__((ext_vector_type(8)));
typedef float f32x4 __attribute__((ext_vector_type(4)));
typedef float f32x16 __attribute__((ext_vector_type(16)));
typedef unsigned short u16x4 __attribute__((ext_vector_type(4)));
typedef unsigned short u16x8 __attribute__((ext_vector_type(8)));

__device__ __forceinline__ unsigned short f2b(float f) {
  return __builtin_bit_cast(unsigned short, (__hip_bfloat16)f);
}
__device__ __forceinline__ unsigned cvtpk(float lo, float hi) {
  unsigned r;
  asm("v_cvt_pk_bf16_f32 %0, %1, %2" : "=v"(r) : "v"(lo), "v"(hi));
  return r;
}
// T12 pair-swap: verified ONLY with two distinct live values (PV path).
// Do NOT use for same-value cross-half reductions (R9/R14/R15 all failed
// identically); use __shfl_xor for those.
__device__ __forceinline__ void pl32swap(unsigned &a, unsigned &b) {
  asm volatile("v_permlane32_swap_b32 %0, %1" : "+v"(a), "+v"(b));
}

// Flash attention fwd, causal, tau-scaled.  R16 = R10 (verified, 53.3us)
// + deferred l-sum ONLY: the per-iteration cross-lane sum reduce
// (ds_bpermute ~120cy) is removed; l_run is a per-lane partial over that
// lane's own kv columns, reduced ONCE in the epilogue. Valid because the
// (kept, proven) cross-half max reduce makes m_run pairwise-equal, so the
// rescale factor corr commutes with the deferred sum.
// Structure: 8 waves, QBLK=128, intra-block even/odd KV-split (waves 0-3
// even 64-kv tiles, 4-7 odd), 32x32x16 MFMA, swapped QK^T, T12 P-routing,
// T13 defer-max, T14 early loads, dbuf swizzled LDS, LDS merge of halves.
__global__ __launch_bounds__(512, 1) void attn_fwd(
    const float* __restrict__ Q, const float* __restrict__ K,
    const float* __restrict__ V, const float* __restrict__ tau,
    float* __restrict__ O)
{
  // balanced remap: CU c gets flat {c, c+256} -> qt {j, 15-j}; (b,h) per
  // flat%32 -> q-tiles of one (b,h) share an XCD.
  const int f  = blockIdx.x + 16 * (blockIdx.y + 8 * blockIdx.z);
  const int u  = f >> 5, hb = f & 31;
  const int h  = hb & 7, b = hb >> 3;
  const int qt = (u < 8) ? u : 23 - u;

  const int tid  = threadIdx.x;
  const int wave = tid >> 6, lane = tid & 63;
  const int l31 = lane & 31, hi = lane >> 5;
  const int l7 = l31 & 7;
  const int half = wave >> 2, wv = wave & 3;   // kv-half, q-subtile

  __shared__ union {
    struct { unsigned short Kt[2][2][64 * 64];   // [half][buf][kv][e]
             unsigned short Vt[2][2][64 * 64]; } kv;  // [half][buf][d][kv]
    struct { float O[128][64]; float m[128]; float l[128]; } cmb;
  } sm;

  const float qscale = 0.125f * expf(tau[b]) * 1.44269504088896f;
  const int q0w = qt * 128 + wv * 32;          // wave's first q-row
  const int myq = q0w + l31;                   // lane's q (dup over hi)
  const int dqd = 32 * wv + l31 - 64 * half;   // diagonal mask bound
  const bool skipw = (half == 1) && (wv < 2);  // fully-masked diagonal tile

  // Q fragments (B operand): qf[ks][j] = Q[myq][16ks + 8hi + j]
  const float* Qb = Q + (((size_t)b * L_ + myq) * H_ + h) * E_;
  bf16x8 qf[4];
  #pragma unroll
  for (int ks = 0; ks < 4; ++ks) {
    f32x4 a = *(const f32x4*)(Qb + ks * 16 + hi * 8);
    f32x4 c = *(const f32x4*)(Qb + ks * 16 + hi * 8 + 4);
    #pragma unroll
    for (int j = 0; j < 4; ++j) {
      qf[ks][j]     = (short)f2b(a[j] * qscale);
      qf[ks][4 + j] = (short)f2b(c[j] * qscale);
    }
  }

  float m_run = -INFINITY, l_run = 0.0f;       // l_run: PER-LANE PARTIAL
  f32x16 oacc[2];
  #pragma unroll
  for (int nd = 0; nd < 2; ++nd)
    #pragma unroll
    for (int r = 0; r < 16; ++r) oacc[nd][r] = 0.0f;

  // ---- staging maps: threads <256 stage half 0, >=256 stage half 1 ----
  const int hs = tid >> 8, st = tid & 255;
  const int krow = st >> 2, kcg = st & 3;
  const int vkv = (st & 15) * 4, vd = (st >> 4) * 4;
  const size_t bh = ((size_t)b * L_ * H_ + h) * E_;
  const float* Kp = K + bh + (size_t)(64 * hs + krow) * HE + kcg * 16;
  const float* Vp = V + bh + (size_t)(64 * hs + vkv) * HE + vd;
  const int kwo0 = krow * 64 + (((2 * kcg)     ^ (krow & 7)) << 3);
  const int kwo1 = krow * 64 + (((2 * kcg + 1) ^ (krow & 7)) << 3);

  const int nt = qt + 1;   // iterations; half h_ sees tiles 2i + h_

  f32x4 kq[4], vq[4];
  // ---- prologue: load + stage tile (2*0 + hs) into buf 0 ----
  #pragma unroll
  for (int i = 0; i < 4; ++i) kq[i] = *(const f32x4*)(Kp + 4 * i);
  #pragma unroll
  for (int i = 0; i < 4; ++i) vq[i] = *(const f32x4*)(Vp + (size_t)i * HE);
  {
    u16x8 w0, w1;
    #pragma unroll
    for (int j = 0; j < 4; ++j) {
      w0[j] = f2b(kq[0][j]); w0[4 + j] = f2b(kq[1][j]);
      w1[j] = f2b(kq[2][j]); w1[4 + j] = f2b(kq[3][j]);
    }
    *(u16x8*)(&sm.kv.Kt[hs][0][kwo0]) = w0;
    *(u16x8*)(&sm.kv.Kt[hs][0][kwo1]) = w1;
    #pragma unroll
    for (int jd = 0; jd < 4; ++jd) {
      const int row = vd + jd;
      u16x4 vw;
      #pragma unroll
      for (int i = 0; i < 4; ++i) vw[i] = f2b(vq[i][jd]);
      *(u16x4*)(&sm.kv.Vt[hs][0][row * 64 + (((vkv >> 3) ^ (row & 7)) << 3) + (vkv & 7)]) = vw;
    }
  }
  __syncthreads();
  int cur = 0;

  for (int t = 0; t < nt; ++t) {
    const bool havenext = (t + 1 < nt);
    if (havenext) {   // T14: issue next-tile loads early, LDS-write late
      const float* Kn = Kp + (size_t)(t + 1) * 128 * HE;
      const float* Vn = Vp + (size_t)(t + 1) * 128 * HE;
      #pragma unroll
      for (int i = 0; i < 4; ++i) kq[i] = *(const f32x4*)(Kn + 4 * i);
      #pragma unroll
      for (int i = 0; i < 4; ++i) vq[i] = *(const f32x4*)(Vn + (size_t)i * HE);
    }

    if (!(skipw && t == nt - 1)) {
      const unsigned short* Kl = sm.kv.Kt[half][cur];
      const unsigned short* Vl = sm.kv.Vt[half][cur];

      // ---- S^T = K Q^T : 8 MFMAs ----
      f32x16 sacc[2];
      #pragma unroll
      for (int mt = 0; mt < 2; ++mt)
        #pragma unroll
        for (int r = 0; r < 16; ++r) sacc[mt][r] = 0.0f;
      __builtin_amdgcn_s_setprio(1);
      #pragma unroll
      for (int ks = 0; ks < 4; ++ks) {
        #pragma unroll
        for (int mt = 0; mt < 2; ++mt) {
          bf16x8 kf = *(const bf16x8*)(Kl + (32 * mt + l31) * 64 +
                                       (((2 * ks + hi) ^ l7) << 3));
          sacc[mt] = __builtin_amdgcn_mfma_f32_32x32x16_bf16(kf, qf[ks], sacc[mt], 0, 0, 0);
        }
      }
      __builtin_amdgcn_s_setprio(0);

      // ---- causal mask (diagonal iteration only) ----
      if (t == nt - 1) {
        #pragma unroll
        for (int mt = 0; mt < 2; ++mt)
          #pragma unroll
          for (int r = 0; r < 16; ++r) {
            const int kvl = 32 * mt + (r & 3) + 8 * (r >> 2) + 4 * hi;
            if (kvl > dqd) sacc[mt][r] = -3.0e38f;
          }
      }

      // ---- online softmax: balanced max tree + defer-max (T13) ----
      float p0 = sacc[0][0], p1 = sacc[0][1], p2 = sacc[0][2], p3 = sacc[0][3];
      #pragma unroll
      for (int mt = 0; mt < 2; ++mt)
        #pragma unroll
        for (int r = (mt == 0 ? 4 : 0); r < 16; r += 4) {
          p0 = fmaxf(p0, sacc[mt][r]);
          p1 = fmaxf(p1, sacc[mt][r + 1]);
          p2 = fmaxf(p2, sacc[mt][r + 2]);
          p3 = fmaxf(p3, sacc[mt][r + 3]);
        }
      float mx = fmaxf(fmaxf(p0, p1), fmaxf(p2, p3));
      mx = fmaxf(mx, __shfl_xor(mx, 32));      // proven cross-half reduce

      if (!__all(mx - m_run <= 8.0f)) {        // rescale needed (rare)
        const float mnew = fmaxf(m_run, mx);
        const float corr = exp2f(m_run - mnew);   // first tile: exp2(-inf)=0
        m_run = mnew;
        l_run *= corr;                         // partial scales uniformly
        #pragma unroll
        for (int r = 0; r < 16; ++r) {
          const int qrow = (r & 3) + 8 * (r >> 2) + 4 * hi;
          const float cr = __shfl(corr, qrow);
          oacc[0][r] *= cr;
          oacc[1][r] *= cr;
        }
      }

      float s0 = 0.f, s1 = 0.f, s2 = 0.f, s3 = 0.f;
      #pragma unroll
      for (int mt = 0; mt < 2; ++mt)
        #pragma unroll
        for (int r = 0; r < 16; r += 4) {
          float e0 = exp2f(sacc[mt][r]     - m_run);
          float e1 = exp2f(sacc[mt][r + 1] - m_run);
          float e2 = exp2f(sacc[mt][r + 2] - m_run);
          float e3 = exp2f(sacc[mt][r + 3] - m_run);
          sacc[mt][r] = e0; sacc[mt][r + 1] = e1;
          sacc[mt][r + 2] = e2; sacc[mt][r + 3] = e3;
          s0 += e0; s1 += e1; s2 += e2; s3 += e3;
        }
      l_run += (s0 + s1) + (s2 + s3);          // DEFERRED: no cross-lane here

      // ---- P -> bf16 packed words (T12 step 1) ----
      unsigned pk[2][8];
      #pragma unroll
      for (int mt = 0; mt < 2; ++mt)
        #pragma unroll
        for (int i = 0; i < 8; ++i)
          pk[mt][i] = cvtpk(sacc[mt][2 * i], sacc[mt][2 * i + 1]);

      // ---- O += P V : 8 MFMAs; pf via permlane32_swap (T12 step 2) ----
      __builtin_amdgcn_s_setprio(1);
      #pragma unroll
      for (int ks = 0; ks < 4; ++ks) {
        const int c = ks & 1, mtx = ks >> 1;
        unsigned a  = pk[mtx][4 * c];
        unsigned y  = pk[mtx][4 * c + 2];
        unsigned a2 = pk[mtx][4 * c + 1];
        unsigned y2 = pk[mtx][4 * c + 3];
        pl32swap(a, y);
        pl32swap(a2, y2);
        union { unsigned w[4]; bf16x8 v; } pu;
        pu.w[0] = a; pu.w[1] = a2; pu.w[2] = y; pu.w[3] = y2;
        #pragma unroll
        for (int nd = 0; nd < 2; ++nd) {
          bf16x8 vf = *(const bf16x8*)(Vl + (32 * nd + l31) * 64 +
                                       (((2 * ks + hi) ^ l7) << 3));
          oacc[nd] = __builtin_amdgcn_mfma_f32_32x32x16_bf16(pu.v, vf, oacc[nd], 0, 0, 0);
        }
      }
      __builtin_amdgcn_s_setprio(0);
    }

    if (havenext) {
      const int nb = cur ^ 1;
      u16x8 w0, w1;
      #pragma unroll
      for (int j = 0; j < 4; ++j) {
        w0[j] = f2b(kq[0][j]); w0[4 + j] = f2b(kq[1][j]);
        w1[j] = f2b(kq[2][j]); w1[4 + j] = f2b(kq[3][j]);
      }
      *(u16x8*)(&sm.kv.Kt[hs][nb][kwo0]) = w0;
      *(u16x8*)(&sm.kv.Kt[hs][nb][kwo1]) = w1;
      #pragma unroll
      for (int jd = 0; jd < 4; ++jd) {
        const int row = vd + jd;
        u16x4 vw;
        #pragma unroll
        for (int i = 0; i < 4; ++i) vw[i] = f2b(vq[i][jd]);
        *(u16x4*)(&sm.kv.Vt[hs][nb][row * 64 + (((vkv >> 3) ^ (row & 7)) << 3) + (vkv & 7)]) = vw;
      }
      __syncthreads();
      cur = nb;
    }
  }

  // ---- epilogue: reduce l partial ONCE, then merge the two kv-halves ----
  l_run += __shfl_xor(l_run, 32);              // deferred sum reduce

  __syncthreads();                  // all compute LDS reads done
  if (half == 1) {                  // publish unnormalized state
    #pragma unroll
    for (int r = 0; r < 16; ++r) {
      const int qrow = (r & 3) + 8 * (r >> 2) + 4 * hi;
      sm.cmb.O[32 * wv + qrow][l31]      = oacc[0][r];
      sm.cmb.O[32 * wv + qrow][32 + l31] = oacc[1][r];
    }
    if (hi == 0) { sm.cmb.m[32 * wv + l31] = m_run; sm.cmb.l[32 * wv + l31] = l_run; }
  }
  __syncthreads();
  if (half == 0) {                  // merge + normalize + store
    const float m_b = sm.cmb.m[32 * wv + l31];
    const float l_b = sm.cmb.l[32 * wv + l31];
    const float mm = fmaxf(m_run, m_b);
    const float sa = exp2f(m_run - mm);
    const float sb = exp2f(m_b - mm);          // m_b=-inf (empty half) -> 0
    const float linv = 1.0f / (sa * l_run + sb * l_b);
    const float wa = sa * linv, wb = sb * linv;
    float* Ob = O + (((size_t)b * L_ + q0w) * H_ + h) * E_;
    #pragma unroll
    for (int r = 0; r < 16; ++r) {
      const int qrow = (r & 3) + 8 * (r >> 2) + 4 * hi;
      const float wa_r = __shfl(wa, qrow);
      const float wb_r = __shfl(wb, qrow);
      Ob[(size_t)qrow * HE + l31] =
          wa_r * oacc[0][r] + wb_r * sm.cmb.O[32 * wv + qrow][l31];
      Ob[(size_t)qrow * HE + 32 + l31] =
          wa_r * oacc[1][r] + wb_r * sm.cmb.O[32 * wv + qrow][32 + l31];
    }
  }
}

extern "C" void kernel_launch(void* const* d_in, const int* in_sizes, int n_in,
                              void* d_out, int out_size, void* d_ws, size_t ws_size,
                              hipStream_t stream) {
  (void)in_sizes; (void)n_in; (void)out_size; (void)d_ws; (void)ws_size;
  const float* Q   = (const float*)d_in[0];
  const float* K   = (const float*)d_in[1];
  const float* V   = (const float*)d_in[2];
  // d_in[3] = attn_mask: ignored, causality applied analytically.
  const float* tau = (const float*)d_in[4];
  float* O = (float*)d_out;
  dim3 grid(16, 8, 4), block(512);
  hipLaunchKernelGGL(attn_fwd, grid, block, 0, stream, Q, K, V, tau, O);
}